// Round 3
// baseline (3952.654 us; speedup 1.0000x reference)
//
#include <hip/hip_runtime.h>
#include <hip/hip_bf16.h>

typedef __hip_bfloat16 bf16;

__device__ __forceinline__ float b2f(bf16 v){ return __bfloat162float(v); }
static inline int imin(int a, int b){ return a < b ? a : b; }

// ---------------------------------------------------------------------------
// Projection: h[n,c] = sum_k x[n,k]*W[k,c] + b[c]; per-head attention dots
// a#[n,h] = sum_{c in head h} h[n,c]*att#[c].
// All inputs FP32 (reference uses jnp.float32 throughout). One node per
// 128-thread block iteration; c = threadIdx.x. Scalar loads, W L1-resident.
template<int K, int NATT, bool STORE_H>
__global__ __launch_bounds__(128) void proj_simple(
    const float* __restrict__ x,      // [N,K]
    const float* __restrict__ W,      // [K,128]
    const float* __restrict__ b,      // [128]
    const float* __restrict__ att0,   // [128]
    const float* __restrict__ att1,   // [128] (NATT==2)
    bf16*  __restrict__ h_out,        // [N,128] bf16 internal (STORE_H)
    float* __restrict__ a0_out,       // [N,8]
    float* __restrict__ a1_out,       // [N,8] (NATT==2)
    int N)
{
    const int c = threadIdx.x;
    __shared__ float xs[K];
    const float bc  = b[c];
    const float a0c = att0[c];
    const float a1c = (NATT == 2) ? att1[c] : 0.f;

    for (int n = blockIdx.x; n < N; n += gridDim.x){
        __syncthreads();
        if (c < K) xs[c] = x[(size_t)n*K + c];
        __syncthreads();
        float acc = bc;
        #pragma unroll 8
        for (int k = 0; k < K; k++)
            acc = fmaf(xs[k], W[k*128 + c], acc);
        if (STORE_H) h_out[(size_t)n*128 + c] = __float2bfloat16(acc);
        // head = c>>4; reduce over the 16 lanes of this head
        float p0 = acc * a0c;
        p0 += __shfl_down(p0, 8, 16);
        p0 += __shfl_down(p0, 4, 16);
        p0 += __shfl_down(p0, 2, 16);
        p0 += __shfl_down(p0, 1, 16);
        if ((c & 15) == 0) a0_out[(size_t)n*8 + (c >> 4)] = p0;
        if (NATT == 2){
            float p1 = acc * a1c;
            p1 += __shfl_down(p1, 8, 16);
            p1 += __shfl_down(p1, 4, 16);
            p1 += __shfl_down(p1, 2, 16);
            p1 += __shfl_down(p1, 1, 16);
            if ((c & 15) == 0) a1_out[(size_t)n*8 + (c >> 4)] = p1;
        }
    }
}

// ---------------------------------------------------------------------------
// Edge aggregation: 128 threads per edge (j = head*16 + dim).
// e = exp(leaky_relu(a_s[src,h]+a_d[dst,h])); atomic-accumulate e into
// s[dst,h] and e*h_src[src,j] into o[dst,j]. Softmax max-pass skipped
// (logits are O(1); clamp is identity on correct data).
__global__ __launch_bounds__(256) void edge_kernel(
    const int* __restrict__ src, const int* __restrict__ dst, int E,
    const float* __restrict__ a_s,    // [Ns,8]
    const float* __restrict__ a_d,    // [Na,8]
    const bf16*  __restrict__ h_src,  // [Ns,128]
    float* __restrict__ s_out,        // [Na,8]
    float* __restrict__ o_out)        // [Na,128]
{
    const int e = blockIdx.x*2 + (threadIdx.x >> 7);
    if (e >= E) return;
    const int j = threadIdx.x & 127;
    const int sN = src[e], dN = dst[e];
    const int h = j >> 4;
    float logit = a_s[(size_t)sN*8 + h] + a_d[(size_t)dN*8 + h];
    logit = logit >= 0.f ? logit : 0.2f*logit;       // leaky_relu(0.2)
    logit = fminf(fmaxf(logit, -30.f), 30.f);
    const float ee = __expf(logit);
    if ((j & 15) == 0) unsafeAtomicAdd(&s_out[(size_t)dN*8 + h], ee);
    unsafeAtomicAdd(&o_out[(size_t)dN*128 + j], ee * b2f(h_src[(size_t)sN*128 + j]));
}

// o[i] = relu(o[i] / (s[node,head] + 1e-16))
__global__ void finalize_kernel(float* __restrict__ o, const float* __restrict__ s, int total)
{
    const int i = blockIdx.x*256 + threadIdx.x;
    if (i >= total) return;
    const float sv = s[(size_t)(i >> 7)*8 + ((i >> 4) & 7)];
    const float v = o[i] / (sv + 1e-16f);
    o[i] = fmaxf(v, 0.f);
}

// ---------------------------------------------------------------------------
// wsum[t,c] = sum_n tanh((o_t[n,:] @ Wk)[c] + bk[c]); one node per block
// iteration, per-thread running column sum, one atomic per thread at end.
__global__ __launch_bounds__(128) void semw_simple(
    const float* __restrict__ o0, const float* __restrict__ o1,
    const float* __restrict__ Wk, const float* __restrict__ bk,
    float* __restrict__ wsum, int Na)
{
    const int c = threadIdx.x;
    const float* __restrict__ o = blockIdx.y ? o1 : o0;
    __shared__ float os[128];
    const float bkc = bk[c];
    float colsum = 0.f;
    for (int n = blockIdx.x; n < Na; n += gridDim.x){
        __syncthreads();
        os[c] = o[(size_t)n*128 + c];
        __syncthreads();
        float acc = bkc;
        #pragma unroll 8
        for (int k = 0; k < 128; k++)
            acc = fmaf(os[k], Wk[k*128 + c], acc);
        colsum += tanhf(acc);
    }
    unsafeAtomicAdd(&wsum[blockIdx.y*128 + c], colsum);
}

// beta = softmax over 2 of ((wsum/Na) . q)
__global__ void beta_kernel(const float* __restrict__ wsum, const float* __restrict__ q,
                            float* __restrict__ beta, float invN)
{
    __shared__ float r0s[128], r1s[128];
    const int tid = threadIdx.x;
    const float qv = q[tid];
    r0s[tid] = wsum[tid]     * invN * qv;
    r1s[tid] = wsum[128+tid] * invN * qv;
    __syncthreads();
    for (int s = 64; s > 0; s >>= 1){
        if (tid < s){ r0s[tid] += r0s[tid+s]; r1s[tid] += r1s[tid+s]; }
        __syncthreads();
    }
    if (tid == 0){
        const float w0 = r0s[0], w1 = r1s[0];
        const float m = fmaxf(w0, w1);
        const float e0 = __expf(w0-m), e1 = __expf(w1-m);
        const float inv = 1.f/(e0+e1);
        beta[0] = e0*inv; beta[1] = e1*inv;
    }
}

// sem = b0*o_pa + b1*o_da; logits = sem @ Wl + bl; softmax -> fp32 [Na,2]
__global__ __launch_bounds__(256) void final_kernel(
    const float* __restrict__ o_pa, const float* __restrict__ o_da,
    const float* __restrict__ beta,
    const float* __restrict__ Wl, const float* __restrict__ bl,
    float* __restrict__ out, int Na)
{
    const int gtid = blockIdx.x*256 + threadIdx.x;
    const int node = gtid >> 6;
    const int lane = threadIdx.x & 63;
    if (node >= Na) return;
    const float b0 = beta[0], b1 = beta[1];
    const size_t base = (size_t)node*128;
    const float s0 = b0*o_pa[base+lane]    + b1*o_da[base+lane];
    const float s1 = b0*o_pa[base+64+lane] + b1*o_da[base+64+lane];
    const float w00 = Wl[lane*2+0],      w01 = Wl[lane*2+1];
    const float w10 = Wl[(lane+64)*2+0], w11 = Wl[(lane+64)*2+1];
    float l0 = s0*w00 + s1*w10;
    float l1 = s0*w01 + s1*w11;
    #pragma unroll
    for (int off = 32; off > 0; off >>= 1){
        l0 += __shfl_down(l0, off);
        l1 += __shfl_down(l1, off);
    }
    if (lane == 0){
        l0 += bl[0]; l1 += bl[1];
        const float m = fmaxf(l0, l1);
        const float e0 = __expf(l0-m), e1 = __expf(l1-m);
        const float inv = 1.f/(e0+e1);
        out[(size_t)node*2+0] = e0*inv;
        out[(size_t)node*2+1] = e1*inv;
    }
}

// ---------------------------------------------------------------------------
extern "C" void kernel_launch(void* const* d_in, const int* in_sizes, int n_in,
                              void* d_out, int out_size, void* d_ws, size_t ws_size,
                              hipStream_t stream)
{
    // Reference dtypes: all float tensors are float32; edges int32.
    const float* x_adm    = (const float*)d_in[0];
    const float* x_pat    = (const float*)d_in[1];
    const float* x_diag   = (const float*)d_in[2];
    const int*   e_pa_src = (const int*)d_in[3];
    const int*   e_pa_dst = (const int*)d_in[4];
    const int*   e_da_src = (const int*)d_in[5];
    const int*   e_da_dst = (const int*)d_in[6];
    const float* Wa = (const float*)d_in[7];
    const float* ba = (const float*)d_in[8];
    const float* Wp = (const float*)d_in[9];
    const float* bp = (const float*)d_in[10];
    const float* Wd = (const float*)d_in[11];
    const float* bd = (const float*)d_in[12];
    const float* ats_pa = (const float*)d_in[13];
    const float* atd_pa = (const float*)d_in[14];
    const float* ats_da = (const float*)d_in[15];
    const float* atd_da = (const float*)d_in[16];
    const float* Wk = (const float*)d_in[17];
    const float* bk = (const float*)d_in[18];
    const float* q  = (const float*)d_in[19];
    const float* Wl = (const float*)d_in[20];
    const float* bl = (const float*)d_in[21];

    const int Na  = in_sizes[0] / 128;
    const int Np  = in_sizes[1] / 64;
    const int Nd  = in_sizes[2] / 64;
    const int Epa = in_sizes[3];
    const int Eda = in_sizes[5];

    float* ws = (float*)d_ws;
    size_t off = 0;
    // --- zero-initialized region (contiguous, one memset) ---
    float* o_pa = ws + off; off += (size_t)Na*128;
    float* o_da = ws + off; off += (size_t)Na*128;
    float* s_pa = ws + off; off += (size_t)Na*8;
    float* s_da = ws + off; off += (size_t)Na*8;
    float* wsum = ws + off; off += 256;
    float* beta = ws + off; off += 8;
    const size_t zero_len = off;
    // --- fully-overwritten region ---
    float* a_s_pa = ws + off; off += (size_t)Np*8;
    float* a_s_da = ws + off; off += (size_t)Nd*8;
    float* a_d_pa = ws + off; off += (size_t)Na*8;
    float* a_d_da = ws + off; off += (size_t)Na*8;
    bf16*  h_p    = (bf16*)(ws + off); off += ((size_t)Np*128 + 1)/2;
    bf16*  h_d    = (bf16*)(ws + off); off += ((size_t)Nd*128 + 1)/2;
    (void)n_in; (void)out_size; (void)ws_size; (void)off;

    hipMemsetAsync(d_ws, 0, zero_len*sizeof(float), stream);

    // projections (+ attention dots). h_adm never materialized.
    proj_simple<128,2,false><<<imin(Na,4096),128,0,stream>>>(
        x_adm, Wa, ba, atd_pa, atd_da, nullptr, a_d_pa, a_d_da, Na);
    proj_simple<64,1,true><<<imin(Np,4096),128,0,stream>>>(
        x_pat, Wp, bp, ats_pa, nullptr, h_p, a_s_pa, nullptr, Np);
    proj_simple<64,1,true><<<imin(Nd,4096),128,0,stream>>>(
        x_diag, Wd, bd, ats_da, nullptr, h_d, a_s_da, nullptr, Nd);

    // edge aggregation (2 edges per 256-thread block)
    edge_kernel<<<(Epa+1)/2, 256, 0, stream>>>(e_pa_src, e_pa_dst, Epa,
                                               a_s_pa, a_d_pa, h_p, s_pa, o_pa);
    edge_kernel<<<(Eda+1)/2, 256, 0, stream>>>(e_da_src, e_da_dst, Eda,
                                               a_s_da, a_d_da, h_d, s_da, o_da);

    // normalize + relu
    {
        const int total = Na*128;
        finalize_kernel<<<(total+255)/256, 256, 0, stream>>>(o_pa, s_pa, total);
        finalize_kernel<<<(total+255)/256, 256, 0, stream>>>(o_da, s_da, total);
    }

    // semantic attention
    {
        dim3 grid(imin(Na,4096), 2);
        semw_simple<<<grid, 128, 0, stream>>>(o_pa, o_da, Wk, bk, wsum, Na);
    }
    beta_kernel<<<1,128,0,stream>>>(wsum, q, beta, 1.f/(float)Na);

    // combine + classifier + softmax
    final_kernel<<<(Na+3)/4, 256, 0, stream>>>(o_pa, o_da, beta, Wl, bl,
                                               (float*)d_out, Na);
}

// Round 4
// 2469.851 us; speedup vs baseline: 1.6004x; 1.6004x over previous
//
#include <hip/hip_runtime.h>
#include <hip/hip_bf16.h>

typedef __hip_bfloat16 bf16;

__device__ __forceinline__ float b2f(bf16 v){ return __bfloat162float(v); }
__device__ __forceinline__ float bfraw2f(unsigned int u){
    union { unsigned int i; float f; } c; c.i = u << 16; return c.f;
}
static inline int imin(int a, int b){ return a < b ? a : b; }

// ---------------------------------------------------------------------------
// Register-blocked projection. Block 256 = 8 rowgroups x 32 colgroups.
// Tile: 32 rows x 128 cols; thread owns 4 rows (rg*4..) x 4 cols (cg*4..).
// x tile staged ROW-MAJOR in LDS (no transpose; inner reads are broadcasts).
// W staged in LDS once per block: bf16 if WB (K=128, 32KB) else fp32.
// Outputs: optional h (bf16), per-head attention dots a#[n,8].
template<int K, int NATT, bool STORE_H, bool WB>
__global__ __launch_bounds__(256) void proj_mt(
    const float* __restrict__ x,      // [N,K]
    const float* __restrict__ W,      // [K,128]
    const float* __restrict__ b,      // [128]
    const float* __restrict__ att0,   // [128]
    const float* __restrict__ att1,   // [128] (NATT==2)
    bf16*  __restrict__ h_out,        // [N,128] (STORE_H)
    float* __restrict__ a0_out,       // [N,8]
    float* __restrict__ a1_out,       // [N,8] (NATT==2)
    int N, int ntiles)
{
    __shared__ float Wsf[WB ? 4 : K*128];
    __shared__ bf16  Wsb[WB ? K*128 : 4];
    __shared__ float xs[32*K];
    const int tid = threadIdx.x;
    const int cg = tid & 31;
    const int rg = tid >> 5;

    if (WB){
        for (int i = tid; i < K*128; i += 256) Wsb[i] = __float2bfloat16(W[i]);
    } else {
        for (int i = tid; i < K*32; i += 256)
            *(float4*)&Wsf[i*4] = *(const float4*)&W[i*4];
    }

    float bc[4], at0v[4], at1v[4] = {0.f,0.f,0.f,0.f};
    #pragma unroll
    for (int u = 0; u < 4; u++){ bc[u] = b[cg*4+u]; at0v[u] = att0[cg*4+u]; }
    if (NATT == 2){
        #pragma unroll
        for (int u = 0; u < 4; u++) at1v[u] = att1[cg*4+u];
    }
    const int head = cg >> 2;

    for (int tile = blockIdx.x; tile < ntiles; tile += gridDim.x){
        const int row0 = tile*32;
        __syncthreads();
        constexpr int C4 = K/4;
        for (int i = tid; i < 32*C4; i += 256){
            const int r  = i / C4;
            const int c4 = (i % C4)*4;
            const int row = row0 + r;
            float4 v = make_float4(0.f,0.f,0.f,0.f);
            if (row < N) v = *(const float4*)&x[(size_t)row*K + c4];
            *(float4*)&xs[r*K + c4] = v;
        }
        __syncthreads();

        float acc[4][4];
        #pragma unroll
        for (int j = 0; j < 4; j++){ acc[j][0]=acc[j][1]=acc[j][2]=acc[j][3]=0.f; }

        #pragma unroll 2
        for (int k0 = 0; k0 < K; k0 += 4){
            float xr[4][4];
            #pragma unroll
            for (int j = 0; j < 4; j++){
                const float4 v = *(const float4*)&xs[(rg*4+j)*K + k0];
                xr[j][0]=v.x; xr[j][1]=v.y; xr[j][2]=v.z; xr[j][3]=v.w;
            }
            float wc[4][4];
            #pragma unroll
            for (int kk = 0; kk < 4; kk++){
                if (WB){
                    unsigned long long raw;
                    __builtin_memcpy(&raw, (const char*)Wsb + ((size_t)((k0+kk)*128 + cg*4)*2), 8);
                    wc[kk][0] = bfraw2f((unsigned int)( raw        & 0xffffu));
                    wc[kk][1] = bfraw2f((unsigned int)((raw >> 16) & 0xffffu));
                    wc[kk][2] = bfraw2f((unsigned int)((raw >> 32) & 0xffffu));
                    wc[kk][3] = bfraw2f((unsigned int)((raw >> 48) & 0xffffu));
                } else {
                    const float4 v = *(const float4*)&Wsf[(k0+kk)*128 + cg*4];
                    wc[kk][0]=v.x; wc[kk][1]=v.y; wc[kk][2]=v.z; wc[kk][3]=v.w;
                }
            }
            #pragma unroll
            for (int kk = 0; kk < 4; kk++)
                #pragma unroll
                for (int j = 0; j < 4; j++){
                    acc[j][0] = fmaf(xr[j][kk], wc[kk][0], acc[j][0]);
                    acc[j][1] = fmaf(xr[j][kk], wc[kk][1], acc[j][1]);
                    acc[j][2] = fmaf(xr[j][kk], wc[kk][2], acc[j][2]);
                    acc[j][3] = fmaf(xr[j][kk], wc[kk][3], acc[j][3]);
                }
        }

        #pragma unroll
        for (int j = 0; j < 4; j++){
            const int row = row0 + rg*4 + j;
            const bool valid = row < N;
            const float h0 = acc[j][0]+bc[0], h1 = acc[j][1]+bc[1];
            const float h2 = acc[j][2]+bc[2], h3 = acc[j][3]+bc[3];
            if (STORE_H && valid){
                h_out[(size_t)row*128 + cg*4+0] = __float2bfloat16(h0);
                h_out[(size_t)row*128 + cg*4+1] = __float2bfloat16(h1);
                h_out[(size_t)row*128 + cg*4+2] = __float2bfloat16(h2);
                h_out[(size_t)row*128 + cg*4+3] = __float2bfloat16(h3);
            }
            float p0 = h0*at0v[0] + h1*at0v[1] + h2*at0v[2] + h3*at0v[3];
            p0 += __shfl_down(p0, 2, 4);
            p0 += __shfl_down(p0, 1, 4);
            if (valid && (cg & 3) == 0) a0_out[(size_t)row*8 + head] = p0;
            if (NATT == 2){
                float p1 = h0*at1v[0] + h1*at1v[1] + h2*at1v[2] + h3*at1v[3];
                p1 += __shfl_down(p1, 2, 4);
                p1 += __shfl_down(p1, 1, 4);
                if (valid && (cg & 3) == 0) a1_out[(size_t)row*8 + head] = p1;
            }
        }
    }
}

// ---------------------------------------------------------------------------
// Edge aggregation: 128 threads per edge (j = head*16 + dim).
__global__ __launch_bounds__(256) void edge_kernel(
    const int* __restrict__ src, const int* __restrict__ dst, int E,
    const float* __restrict__ a_s,    // [Ns,8]
    const float* __restrict__ a_d,    // [Na,8]
    const bf16*  __restrict__ h_src,  // [Ns,128]
    float* __restrict__ s_out,        // [Na,8]
    float* __restrict__ o_out)        // [Na,128]
{
    const int e = blockIdx.x*2 + (threadIdx.x >> 7);
    if (e >= E) return;
    const int j = threadIdx.x & 127;
    const int sN = src[e], dN = dst[e];
    const int h = j >> 4;
    float logit = a_s[(size_t)sN*8 + h] + a_d[(size_t)dN*8 + h];
    logit = logit >= 0.f ? logit : 0.2f*logit;       // leaky_relu(0.2)
    logit = fminf(fmaxf(logit, -30.f), 30.f);
    const float ee = __expf(logit);
    if ((j & 15) == 0) unsafeAtomicAdd(&s_out[(size_t)dN*8 + h], ee);
    unsafeAtomicAdd(&o_out[(size_t)dN*128 + j], ee * b2f(h_src[(size_t)sN*128 + j]));
}

// ---------------------------------------------------------------------------
// Semantic attention GEMM, register-blocked; normalization (o/s, relu) fused
// into the staging loads. wsum[t,c] += sum_n tanh((o_n @ Wk)[c] + bk[c]).
__global__ __launch_bounds__(256) void semw_mt(
    const float* __restrict__ o0, const float* __restrict__ o1,
    const float* __restrict__ s0, const float* __restrict__ s1,
    const float* __restrict__ Wk, const float* __restrict__ bk,
    float* __restrict__ wsum, int Na, int ntiles)
{
    __shared__ bf16  Wsb[128*128];
    __shared__ float xs[32*128];
    const int tid = threadIdx.x;
    const int cg = tid & 31;
    const int rg = tid >> 5;
    const float* __restrict__ o = blockIdx.y ? o1 : o0;
    const float* __restrict__ s = blockIdx.y ? s1 : s0;

    for (int i = tid; i < 128*128; i += 256) Wsb[i] = __float2bfloat16(Wk[i]);

    float bkc[4];
    #pragma unroll
    for (int u = 0; u < 4; u++) bkc[u] = bk[cg*4+u];
    float colsum[4] = {0.f,0.f,0.f,0.f};

    for (int tile = blockIdx.x; tile < ntiles; tile += gridDim.x){
        const int row0 = tile*32;
        __syncthreads();
        for (int i = tid; i < 1024; i += 256){
            const int r  = i >> 5;
            const int c4 = (i & 31)*4;
            const int row = row0 + r;
            float4 v = make_float4(0.f,0.f,0.f,0.f);
            if (row < Na){
                v = *(const float4*)&o[(size_t)row*128 + c4];
                const float inv = 1.f/(s[(size_t)row*8 + (c4 >> 4)] + 1e-16f);
                v.x = fmaxf(v.x*inv, 0.f); v.y = fmaxf(v.y*inv, 0.f);
                v.z = fmaxf(v.z*inv, 0.f); v.w = fmaxf(v.w*inv, 0.f);
            }
            *(float4*)&xs[r*128 + c4] = v;
        }
        __syncthreads();

        float acc[4][4];
        #pragma unroll
        for (int j = 0; j < 4; j++){ acc[j][0]=acc[j][1]=acc[j][2]=acc[j][3]=0.f; }

        #pragma unroll 2
        for (int k0 = 0; k0 < 128; k0 += 4){
            float xr[4][4];
            #pragma unroll
            for (int j = 0; j < 4; j++){
                const float4 v = *(const float4*)&xs[(rg*4+j)*128 + k0];
                xr[j][0]=v.x; xr[j][1]=v.y; xr[j][2]=v.z; xr[j][3]=v.w;
            }
            float wc[4][4];
            #pragma unroll
            for (int kk = 0; kk < 4; kk++){
                unsigned long long raw;
                __builtin_memcpy(&raw, (const char*)Wsb + ((size_t)((k0+kk)*128 + cg*4)*2), 8);
                wc[kk][0] = bfraw2f((unsigned int)( raw        & 0xffffu));
                wc[kk][1] = bfraw2f((unsigned int)((raw >> 16) & 0xffffu));
                wc[kk][2] = bfraw2f((unsigned int)((raw >> 32) & 0xffffu));
                wc[kk][3] = bfraw2f((unsigned int)((raw >> 48) & 0xffffu));
            }
            #pragma unroll
            for (int kk = 0; kk < 4; kk++)
                #pragma unroll
                for (int j = 0; j < 4; j++){
                    acc[j][0] = fmaf(xr[j][kk], wc[kk][0], acc[j][0]);
                    acc[j][1] = fmaf(xr[j][kk], wc[kk][1], acc[j][1]);
                    acc[j][2] = fmaf(xr[j][kk], wc[kk][2], acc[j][2]);
                    acc[j][3] = fmaf(xr[j][kk], wc[kk][3], acc[j][3]);
                }
        }

        #pragma unroll
        for (int j = 0; j < 4; j++){
            const int row = row0 + rg*4 + j;
            if (row < Na){
                colsum[0] += tanhf(acc[j][0]+bkc[0]);
                colsum[1] += tanhf(acc[j][1]+bkc[1]);
                colsum[2] += tanhf(acc[j][2]+bkc[2]);
                colsum[3] += tanhf(acc[j][3]+bkc[3]);
            }
        }
    }
    float* wdst = wsum + blockIdx.y*128;
    unsafeAtomicAdd(&wdst[cg*4+0], colsum[0]);
    unsafeAtomicAdd(&wdst[cg*4+1], colsum[1]);
    unsafeAtomicAdd(&wdst[cg*4+2], colsum[2]);
    unsafeAtomicAdd(&wdst[cg*4+3], colsum[3]);
}

// beta = softmax over 2 of ((wsum/Na) . q)
__global__ void beta_kernel(const float* __restrict__ wsum, const float* __restrict__ q,
                            float* __restrict__ beta, float invN)
{
    __shared__ float r0s[128], r1s[128];
    const int tid = threadIdx.x;
    const float qv = q[tid];
    r0s[tid] = wsum[tid]     * invN * qv;
    r1s[tid] = wsum[128+tid] * invN * qv;
    __syncthreads();
    for (int st = 64; st > 0; st >>= 1){
        if (tid < st){ r0s[tid] += r0s[tid+st]; r1s[tid] += r1s[tid+st]; }
        __syncthreads();
    }
    if (tid == 0){
        const float w0 = r0s[0], w1 = r1s[0];
        const float m = fmaxf(w0, w1);
        const float e0 = __expf(w0-m), e1 = __expf(w1-m);
        const float inv = 1.f/(e0+e1);
        beta[0] = e0*inv; beta[1] = e1*inv;
    }
}

// sem = b0*relu(o_pa/s_pa) + b1*relu(o_da/s_da); logits=sem@Wl+bl; softmax
__global__ __launch_bounds__(256) void final_kernel(
    const float* __restrict__ o_pa, const float* __restrict__ o_da,
    const float* __restrict__ s_pa, const float* __restrict__ s_da,
    const float* __restrict__ beta,
    const float* __restrict__ Wl, const float* __restrict__ bl,
    float* __restrict__ out, int Na)
{
    const int gtid = blockIdx.x*256 + threadIdx.x;
    const int node = gtid >> 6;
    const int lane = threadIdx.x & 63;
    if (node >= Na) return;
    const float b0 = beta[0], b1 = beta[1];
    const size_t base = (size_t)node*128;
    const int hA = lane >> 4, hB = (lane+64) >> 4;
    const float ipA = 1.f/(s_pa[(size_t)node*8+hA]+1e-16f);
    const float ipB = 1.f/(s_pa[(size_t)node*8+hB]+1e-16f);
    const float idA = 1.f/(s_da[(size_t)node*8+hA]+1e-16f);
    const float idB = 1.f/(s_da[(size_t)node*8+hB]+1e-16f);
    const float pa0 = fmaxf(o_pa[base+lane]   *ipA, 0.f);
    const float pa1 = fmaxf(o_pa[base+64+lane]*ipB, 0.f);
    const float da0 = fmaxf(o_da[base+lane]   *idA, 0.f);
    const float da1 = fmaxf(o_da[base+64+lane]*idB, 0.f);
    const float sm0 = b0*pa0 + b1*da0;
    const float sm1 = b0*pa1 + b1*da1;
    const float w00 = Wl[lane*2+0],      w01 = Wl[lane*2+1];
    const float w10 = Wl[(lane+64)*2+0], w11 = Wl[(lane+64)*2+1];
    float l0 = sm0*w00 + sm1*w10;
    float l1 = sm0*w01 + sm1*w11;
    #pragma unroll
    for (int off = 32; off > 0; off >>= 1){
        l0 += __shfl_down(l0, off);
        l1 += __shfl_down(l1, off);
    }
    if (lane == 0){
        l0 += bl[0]; l1 += bl[1];
        const float m = fmaxf(l0, l1);
        const float e0 = __expf(l0-m), e1 = __expf(l1-m);
        const float inv = 1.f/(e0+e1);
        out[(size_t)node*2+0] = e0*inv;
        out[(size_t)node*2+1] = e1*inv;
    }
}

// ---------------------------------------------------------------------------
extern "C" void kernel_launch(void* const* d_in, const int* in_sizes, int n_in,
                              void* d_out, int out_size, void* d_ws, size_t ws_size,
                              hipStream_t stream)
{
    const float* x_adm    = (const float*)d_in[0];
    const float* x_pat    = (const float*)d_in[1];
    const float* x_diag   = (const float*)d_in[2];
    const int*   e_pa_src = (const int*)d_in[3];
    const int*   e_pa_dst = (const int*)d_in[4];
    const int*   e_da_src = (const int*)d_in[5];
    const int*   e_da_dst = (const int*)d_in[6];
    const float* Wa = (const float*)d_in[7];
    const float* ba = (const float*)d_in[8];
    const float* Wp = (const float*)d_in[9];
    const float* bp = (const float*)d_in[10];
    const float* Wd = (const float*)d_in[11];
    const float* bd = (const float*)d_in[12];
    const float* ats_pa = (const float*)d_in[13];
    const float* atd_pa = (const float*)d_in[14];
    const float* ats_da = (const float*)d_in[15];
    const float* atd_da = (const float*)d_in[16];
    const float* Wk = (const float*)d_in[17];
    const float* bk = (const float*)d_in[18];
    const float* q  = (const float*)d_in[19];
    const float* Wl = (const float*)d_in[20];
    const float* bl = (const float*)d_in[21];

    const int Na  = in_sizes[0] / 128;
    const int Np  = in_sizes[1] / 64;
    const int Nd  = in_sizes[2] / 64;
    const int Epa = in_sizes[3];
    const int Eda = in_sizes[5];

    float* ws = (float*)d_ws;
    size_t off = 0;
    // --- zero-initialized region (contiguous, one memset) ---
    float* o_pa = ws + off; off += (size_t)Na*128;
    float* o_da = ws + off; off += (size_t)Na*128;
    float* s_pa = ws + off; off += (size_t)Na*8;
    float* s_da = ws + off; off += (size_t)Na*8;
    float* wsum = ws + off; off += 256;
    float* beta = ws + off; off += 8;
    const size_t zero_len = off;
    // --- fully-overwritten region ---
    float* a_s_pa = ws + off; off += (size_t)Np*8;
    float* a_s_da = ws + off; off += (size_t)Nd*8;
    float* a_d_pa = ws + off; off += (size_t)Na*8;
    float* a_d_da = ws + off; off += (size_t)Na*8;
    bf16*  h_p    = (bf16*)(ws + off); off += ((size_t)Np*128 + 1)/2;
    bf16*  h_d    = (bf16*)(ws + off); off += ((size_t)Nd*128 + 1)/2;
    (void)n_in; (void)out_size; (void)ws_size; (void)off;

    hipMemsetAsync(d_ws, 0, zero_len*sizeof(float), stream);

    // projections (+ attention dots). h_adm never materialized.
    {
        const int nt = (Na + 31)/32;
        proj_mt<128,2,false,true><<<imin(nt,768),256,0,stream>>>(
            x_adm, Wa, ba, atd_pa, atd_da, nullptr, a_d_pa, a_d_da, Na, nt);
    }
    {
        const int nt = (Np + 31)/32;
        proj_mt<64,1,true,false><<<imin(nt,1024),256,0,stream>>>(
            x_pat, Wp, bp, ats_pa, nullptr, h_p, a_s_pa, nullptr, Np, nt);
    }
    {
        const int nt = (Nd + 31)/32;
        proj_mt<64,1,true,false><<<imin(nt,1024),256,0,stream>>>(
            x_diag, Wd, bd, ats_da, nullptr, h_d, a_s_da, nullptr, Nd, nt);
    }

    // edge aggregation (2 edges per 256-thread block)
    edge_kernel<<<(Epa+1)/2, 256, 0, stream>>>(e_pa_src, e_pa_dst, Epa,
                                               a_s_pa, a_d_pa, h_p, s_pa, o_pa);
    edge_kernel<<<(Eda+1)/2, 256, 0, stream>>>(e_da_src, e_da_dst, Eda,
                                               a_s_da, a_d_da, h_d, s_da, o_da);

    // semantic attention (normalization fused into staging)
    {
        const int nt = (Na + 31)/32;
        dim3 grid(imin(nt,384), 2);
        semw_mt<<<grid, 256, 0, stream>>>(o_pa, o_da, s_pa, s_da, Wk, bk, wsum, Na, nt);
    }
    beta_kernel<<<1,128,0,stream>>>(wsum, q, beta, 1.f/(float)Na);

    // combine (normalization fused) + classifier + softmax
    final_kernel<<<(Na+3)/4, 256, 0, stream>>>(o_pa, o_da, s_pa, s_da, beta,
                                               Wl, bl, (float*)d_out, Na);
}

// Round 5
// 1892.776 us; speedup vs baseline: 2.0883x; 1.3049x over previous
//
#include <hip/hip_runtime.h>
#include <hip/hip_bf16.h>

typedef __hip_bfloat16 bf16;
typedef __attribute__((ext_vector_type(8))) short frag_ab;   // 8 bf16
typedef __attribute__((ext_vector_type(4))) float frag_cd;   // 4 fp32

__device__ __forceinline__ float b2f(bf16 v){ return __bfloat162float(v); }
__device__ __forceinline__ short f2bs(float f){
    bf16 h = __float2bfloat16(f); short s; __builtin_memcpy(&s, &h, 2); return s;
}
__device__ __forceinline__ unsigned pack2(float a, float b){
    return (unsigned)(unsigned short)f2bs(a) | (((unsigned)(unsigned short)f2bs(b)) << 16);
}
static inline int imin(int a, int b){ return a < b ? a : b; }

// ---------------------------------------------------------------------------
// Fold attention vectors into projection weights:
// Wf[k,g] = sum_d Wa[k,(g&7)*16+d] * att_g[(g&7)*16+d],  att_g = atd_pa (g<8) / atd_da
// bdot[g] = sum_d ba[(g&7)*16+d] * att_g[(g&7)*16+d]
__global__ void prep_fold(const float* __restrict__ Wa, const float* __restrict__ ba,
                          const float* __restrict__ atd_pa, const float* __restrict__ atd_da,
                          float* __restrict__ Wf, float* __restrict__ bdot)
{
    const int k = threadIdx.x;  // 0..127
    for (int g = 0; g < 16; g++){
        const float* att = (g < 8) ? atd_pa : atd_da;
        const int h = g & 7;
        float ssum = 0.f;
        for (int d = 0; d < 16; d++)
            ssum += Wa[k*128 + h*16 + d] * att[h*16 + d];
        Wf[k*16 + g] = ssum;
    }
    if (k < 16){
        const float* att = (k < 8) ? atd_pa : atd_da;
        const int h = k & 7;
        float sb = 0.f;
        for (int d = 0; d < 16; d++) sb += ba[h*16 + d] * att[h*16 + d];
        bdot[k] = sb;
    }
}

// ---------------------------------------------------------------------------
// Thin GEMM: a_d[n,g] = x[n,:] @ Wf[:,g] + bdot[g]   (g<8 -> a_pa, else a_da)
// Block 256 = 16 nodes x 16 g. x tile + WfT staged in LDS (stride 132).
__global__ __launch_bounds__(256) void afold_kernel(
    const float* __restrict__ x,     // [Na,128]
    const float* __restrict__ Wf,    // [128,16]
    const float* __restrict__ bdot,  // [16]
    float* __restrict__ a_pa,        // [Na,8]
    float* __restrict__ a_da,        // [Na,8]
    int Na, int ntiles)
{
    __shared__ float WfT[16*132];
    __shared__ float xsr[16*132];
    __shared__ float bs[16];
    const int tid = threadIdx.x;
    for (int i = tid; i < 2048; i += 256){
        const int k = i >> 4, g = i & 15;
        WfT[g*132 + k] = Wf[k*16 + g];
    }
    if (tid < 16) bs[tid] = bdot[tid];
    const int r = tid >> 4, g = tid & 15;

    for (int tile = blockIdx.x; tile < ntiles; tile += gridDim.x){
        const int row0 = tile*16;
        __syncthreads();
        for (int i = tid; i < 512; i += 256){
            const int rr = i >> 5, c4 = (i & 31)*4;
            const int row = row0 + rr;
            float4 v = make_float4(0.f,0.f,0.f,0.f);
            if (row < Na) v = *(const float4*)&x[(size_t)row*128 + c4];
            *(float4*)&xsr[rr*132 + c4] = v;
        }
        __syncthreads();
        float acc = bs[g];
        #pragma unroll 4
        for (int k0 = 0; k0 < 128; k0 += 4){
            const float4 xv = *(const float4*)&xsr[r*132 + k0];
            const float4 wv = *(const float4*)&WfT[g*132 + k0];
            acc += xv.x*wv.x + xv.y*wv.y + xv.z*wv.z + xv.w*wv.w;
        }
        const int row = row0 + r;
        if (row < Na){
            if (g < 8) a_pa[(size_t)row*8 + g]     = acc;
            else       a_da[(size_t)row*8 + (g-8)] = acc;
        }
    }
}

// ---------------------------------------------------------------------------
// Projection for pat/diag (K=64): h = x@W+b (stored bf16), a_s dots.
// Register-blocked 4x4 microtile, W fp32 in LDS (32KB), xs 8KB.
__global__ __launch_bounds__(256) void proj64(
    const float* __restrict__ x,      // [N,64]
    const float* __restrict__ W,      // [64,128]
    const float* __restrict__ b,      // [128]
    const float* __restrict__ att0,   // [128]
    bf16*  __restrict__ h_out,        // [N,128]
    float* __restrict__ a0_out,       // [N,8]
    int N, int ntiles)
{
    constexpr int K = 64;
    __shared__ float Wsf[K*128];
    __shared__ float xs[32*K];
    const int tid = threadIdx.x;
    const int cg = tid & 31;
    const int rg = tid >> 5;

    for (int i = tid; i < K*32; i += 256)
        *(float4*)&Wsf[i*4] = *(const float4*)&W[i*4];

    float bc[4], at0v[4];
    #pragma unroll
    for (int u = 0; u < 4; u++){ bc[u] = b[cg*4+u]; at0v[u] = att0[cg*4+u]; }
    const int head = cg >> 2;

    for (int tile = blockIdx.x; tile < ntiles; tile += gridDim.x){
        const int row0 = tile*32;
        __syncthreads();
        for (int i = tid; i < 32*(K/4); i += 256){
            const int r  = i / (K/4);
            const int c4 = (i % (K/4))*4;
            const int row = row0 + r;
            float4 v = make_float4(0.f,0.f,0.f,0.f);
            if (row < N) v = *(const float4*)&x[(size_t)row*K + c4];
            *(float4*)&xs[r*K + c4] = v;
        }
        __syncthreads();

        float acc[4][4];
        #pragma unroll
        for (int j = 0; j < 4; j++){ acc[j][0]=acc[j][1]=acc[j][2]=acc[j][3]=0.f; }

        #pragma unroll 2
        for (int k0 = 0; k0 < K; k0 += 4){
            float xr[4][4];
            #pragma unroll
            for (int j = 0; j < 4; j++){
                const float4 v = *(const float4*)&xs[(rg*4+j)*K + k0];
                xr[j][0]=v.x; xr[j][1]=v.y; xr[j][2]=v.z; xr[j][3]=v.w;
            }
            #pragma unroll
            for (int kk = 0; kk < 4; kk++){
                const float4 wv = *(const float4*)&Wsf[(k0+kk)*128 + cg*4];
                #pragma unroll
                for (int j = 0; j < 4; j++){
                    acc[j][0] = fmaf(xr[j][kk], wv.x, acc[j][0]);
                    acc[j][1] = fmaf(xr[j][kk], wv.y, acc[j][1]);
                    acc[j][2] = fmaf(xr[j][kk], wv.z, acc[j][2]);
                    acc[j][3] = fmaf(xr[j][kk], wv.w, acc[j][3]);
                }
            }
        }

        #pragma unroll
        for (int j = 0; j < 4; j++){
            const int row = row0 + rg*4 + j;
            const bool valid = row < N;
            const float h0 = acc[j][0]+bc[0], h1 = acc[j][1]+bc[1];
            const float h2 = acc[j][2]+bc[2], h3 = acc[j][3]+bc[3];
            if (valid){
                h_out[(size_t)row*128 + cg*4+0] = __float2bfloat16(h0);
                h_out[(size_t)row*128 + cg*4+1] = __float2bfloat16(h1);
                h_out[(size_t)row*128 + cg*4+2] = __float2bfloat16(h2);
                h_out[(size_t)row*128 + cg*4+3] = __float2bfloat16(h3);
            }
            float p0 = h0*at0v[0] + h1*at0v[1] + h2*at0v[2] + h3*at0v[3];
            p0 += __shfl_down(p0, 2, 4);
            p0 += __shfl_down(p0, 1, 4);
            if (valid && (cg & 3) == 0) a0_out[(size_t)row*8 + head] = p0;
        }
    }
}

// ---------------------------------------------------------------------------
// Edge aggregation: 128 threads per edge (j = head*16 + dim).
__global__ __launch_bounds__(256) void edge_kernel(
    const int* __restrict__ src, const int* __restrict__ dst, int E,
    const float* __restrict__ a_s,    // [Ns,8]
    const float* __restrict__ a_d,    // [Na,8]
    const bf16*  __restrict__ h_src,  // [Ns,128]
    float* __restrict__ s_out,        // [Na,8]
    float* __restrict__ o_out)        // [Na,128]
{
    const int e = blockIdx.x*2 + (threadIdx.x >> 7);
    if (e >= E) return;
    const int j = threadIdx.x & 127;
    const int sN = src[e], dN = dst[e];
    const int h = j >> 4;
    float logit = a_s[(size_t)sN*8 + h] + a_d[(size_t)dN*8 + h];
    logit = logit >= 0.f ? logit : 0.2f*logit;       // leaky_relu(0.2)
    logit = fminf(fmaxf(logit, -30.f), 30.f);
    const float ee = __expf(logit);
    if ((j & 15) == 0) unsafeAtomicAdd(&s_out[(size_t)dN*8 + h], ee);
    unsafeAtomicAdd(&o_out[(size_t)dN*128 + j], ee * b2f(h_src[(size_t)sN*128 + j]));
}

// ---------------------------------------------------------------------------
// Semantic attention GEMM via bf16 MFMA 16x16x32.
// wsum[t,c] += sum_n tanh((relu(o_n/s_n) @ Wk)[c] + bk[c]).
// Block 256 = 4 waves; tile = 64 nodes (wave w -> rows w*16..w*16+15).
// Wk pre-staged in B-fragment layout; o staged row-major bf16 (stride 136).
__global__ __launch_bounds__(256) void semw_mfma(
    const float* __restrict__ o0, const float* __restrict__ o1,
    const float* __restrict__ s0, const float* __restrict__ s1,
    const float* __restrict__ Wk, const float* __restrict__ bk,
    float* __restrict__ wsum, int Na, int ntiles)
{
    __shared__ short Bs[4*8*64*8];     // [k0i][n0i][lane][j] bf16, 32KB
    __shared__ short As[64*136];       // 64 rows x K=128 (stride 136), 17KB
    const int tid  = threadIdx.x;
    const int lane = tid & 63;
    const int w    = tid >> 6;
    const int quad = lane >> 4;
    const int m16  = lane & 15;
    const float* __restrict__ o = blockIdx.y ? o1 : o0;
    const float* __restrict__ s = blockIdx.y ? s1 : s0;

    // stage Wk in B-operand fragment layout: lane holds B[k=quad*8+j][n=lane&15]
    for (int idx = tid; idx < 16384; idx += 256){
        const int j   = idx & 7;
        const int ln  = (idx >> 3) & 63;
        const int n0i = (idx >> 9) & 7;
        const int k0i = idx >> 12;
        const int k = k0i*32 + (ln >> 4)*8 + j;
        const int n = n0i*16 + (ln & 15);
        Bs[idx] = f2bs(Wk[k*128 + n]);
    }

    float bkc[8];
    #pragma unroll
    for (int n0i = 0; n0i < 8; n0i++) bkc[n0i] = bk[n0i*16 + m16];

    float colsum[8] = {0.f,0.f,0.f,0.f,0.f,0.f,0.f,0.f};

    for (int tile = blockIdx.x; tile < ntiles; tile += gridDim.x){
        const int row0 = tile*64;
        __syncthreads();
        // stage 64 rows of o: normalize + relu + bf16
        for (int i = tid; i < 64*32; i += 256){
            const int r  = i >> 5;
            const int c4 = (i & 31)*4;
            const int row = row0 + r;
            float4 v = make_float4(0.f,0.f,0.f,0.f);
            if (row < Na){
                v = *(const float4*)&o[(size_t)row*128 + c4];
                const float inv = 1.f/(s[(size_t)row*8 + (c4>>4)] + 1e-16f);
                v.x = fmaxf(v.x*inv,0.f); v.y = fmaxf(v.y*inv,0.f);
                v.z = fmaxf(v.z*inv,0.f); v.w = fmaxf(v.w*inv,0.f);
            }
            const unsigned u0 = pack2(v.x, v.y);
            const unsigned u1 = pack2(v.z, v.w);
            uint2 uu = make_uint2(u0, u1);
            __builtin_memcpy(&As[r*136 + c4], &uu, 8);
        }
        __syncthreads();

        frag_cd acc[8];
        #pragma unroll
        for (int n0i = 0; n0i < 8; n0i++) acc[n0i] = (frag_cd){0.f,0.f,0.f,0.f};

        #pragma unroll
        for (int k0i = 0; k0i < 4; k0i++){
            // A[m=lane&15][k = k0i*32 + quad*8 + j], row-major contiguous
            frag_ab av = *(const frag_ab*)&As[(w*16 + m16)*136 + k0i*32 + quad*8];
            #pragma unroll
            for (int n0i = 0; n0i < 8; n0i++){
                frag_ab bv = *(const frag_ab*)&Bs[((k0i*8 + n0i)*64 + lane)*8];
                acc[n0i] = __builtin_amdgcn_mfma_f32_16x16x32_bf16(av, bv, acc[n0i], 0, 0, 0);
            }
        }

        // D: row = quad*4 + reg, col = n0i*16 + m16. tanh then column-sum.
        #pragma unroll
        for (int n0i = 0; n0i < 8; n0i++){
            float part = 0.f;
            #pragma unroll
            for (int r = 0; r < 4; r++){
                const int row = row0 + w*16 + quad*4 + r;
                if (row < Na) part += tanhf(acc[n0i][r] + bkc[n0i]);
            }
            part += __shfl_down(part, 32);
            part += __shfl_down(part, 16);
            if (lane < 16) colsum[n0i] += part;
        }
    }
    if (lane < 16){
        float* wdst = wsum + blockIdx.y*128;
        #pragma unroll
        for (int n0i = 0; n0i < 8; n0i++)
            unsafeAtomicAdd(&wdst[n0i*16 + lane], colsum[n0i]);
    }
}

// beta = softmax over 2 of ((wsum/Na) . q)
__global__ void beta_kernel(const float* __restrict__ wsum, const float* __restrict__ q,
                            float* __restrict__ beta, float invN)
{
    __shared__ float r0s[128], r1s[128];
    const int tid = threadIdx.x;
    const float qv = q[tid];
    r0s[tid] = wsum[tid]     * invN * qv;
    r1s[tid] = wsum[128+tid] * invN * qv;
    __syncthreads();
    for (int st = 64; st > 0; st >>= 1){
        if (tid < st){ r0s[tid] += r0s[tid+st]; r1s[tid] += r1s[tid+st]; }
        __syncthreads();
    }
    if (tid == 0){
        const float w0 = r0s[0], w1 = r1s[0];
        const float m = fmaxf(w0, w1);
        const float e0 = __expf(w0-m), e1 = __expf(w1-m);
        const float inv = 1.f/(e0+e1);
        beta[0] = e0*inv; beta[1] = e1*inv;
    }
}

// sem = b0*relu(o_pa/s_pa) + b1*relu(o_da/s_da); logits=sem@Wl+bl; softmax
__global__ __launch_bounds__(256) void final_kernel(
    const float* __restrict__ o_pa, const float* __restrict__ o_da,
    const float* __restrict__ s_pa, const float* __restrict__ s_da,
    const float* __restrict__ beta,
    const float* __restrict__ Wl, const float* __restrict__ bl,
    float* __restrict__ out, int Na)
{
    const int gtid = blockIdx.x*256 + threadIdx.x;
    const int node = gtid >> 6;
    const int lane = threadIdx.x & 63;
    if (node >= Na) return;
    const float b0 = beta[0], b1 = beta[1];
    const size_t base = (size_t)node*128;
    const int hA = lane >> 4, hB = (lane+64) >> 4;
    const float ipA = 1.f/(s_pa[(size_t)node*8+hA]+1e-16f);
    const float ipB = 1.f/(s_pa[(size_t)node*8+hB]+1e-16f);
    const float idA = 1.f/(s_da[(size_t)node*8+hA]+1e-16f);
    const float idB = 1.f/(s_da[(size_t)node*8+hB]+1e-16f);
    const float pa0 = fmaxf(o_pa[base+lane]   *ipA, 0.f);
    const float pa1 = fmaxf(o_pa[base+64+lane]*ipB, 0.f);
    const float da0 = fmaxf(o_da[base+lane]   *idA, 0.f);
    const float da1 = fmaxf(o_da[base+64+lane]*idB, 0.f);
    const float sm0 = b0*pa0 + b1*da0;
    const float sm1 = b0*pa1 + b1*da1;
    const float w00 = Wl[lane*2+0],      w01 = Wl[lane*2+1];
    const float w10 = Wl[(lane+64)*2+0], w11 = Wl[(lane+64)*2+1];
    float l0 = sm0*w00 + sm1*w10;
    float l1 = sm0*w01 + sm1*w11;
    #pragma unroll
    for (int off = 32; off > 0; off >>= 1){
        l0 += __shfl_down(l0, off);
        l1 += __shfl_down(l1, off);
    }
    if (lane == 0){
        l0 += bl[0]; l1 += bl[1];
        const float m = fmaxf(l0, l1);
        const float e0 = __expf(l0-m), e1 = __expf(l1-m);
        const float inv = 1.f/(e0+e1);
        out[(size_t)node*2+0] = e0*inv;
        out[(size_t)node*2+1] = e1*inv;
    }
}

// ---------------------------------------------------------------------------
extern "C" void kernel_launch(void* const* d_in, const int* in_sizes, int n_in,
                              void* d_out, int out_size, void* d_ws, size_t ws_size,
                              hipStream_t stream)
{
    const float* x_adm    = (const float*)d_in[0];
    const float* x_pat    = (const float*)d_in[1];
    const float* x_diag   = (const float*)d_in[2];
    const int*   e_pa_src = (const int*)d_in[3];
    const int*   e_pa_dst = (const int*)d_in[4];
    const int*   e_da_src = (const int*)d_in[5];
    const int*   e_da_dst = (const int*)d_in[6];
    const float* Wa = (const float*)d_in[7];
    const float* ba = (const float*)d_in[8];
    const float* Wp = (const float*)d_in[9];
    const float* bp = (const float*)d_in[10];
    const float* Wd = (const float*)d_in[11];
    const float* bd = (const float*)d_in[12];
    const float* ats_pa = (const float*)d_in[13];
    const float* atd_pa = (const float*)d_in[14];
    const float* ats_da = (const float*)d_in[15];
    const float* atd_da = (const float*)d_in[16];
    const float* Wk = (const float*)d_in[17];
    const float* bk = (const float*)d_in[18];
    const float* q  = (const float*)d_in[19];
    const float* Wl = (const float*)d_in[20];
    const float* bl = (const float*)d_in[21];

    const int Na  = in_sizes[0] / 128;
    const int Np  = in_sizes[1] / 64;
    const int Nd  = in_sizes[2] / 64;
    const int Epa = in_sizes[3];
    const int Eda = in_sizes[5];

    float* ws = (float*)d_ws;
    size_t off = 0;
    // --- zero-initialized region (contiguous, one memset) ---
    float* o_pa = ws + off; off += (size_t)Na*128;
    float* o_da = ws + off; off += (size_t)Na*128;
    float* s_pa = ws + off; off += (size_t)Na*8;
    float* s_da = ws + off; off += (size_t)Na*8;
    float* wsum = ws + off; off += 256;
    float* beta = ws + off; off += 8;
    const size_t zero_len = off;
    // --- fully-overwritten region ---
    float* a_s_pa = ws + off; off += (size_t)Np*8;
    float* a_s_da = ws + off; off += (size_t)Nd*8;
    float* a_d_pa = ws + off; off += (size_t)Na*8;
    float* a_d_da = ws + off; off += (size_t)Na*8;
    float* Wf     = ws + off; off += 2048;
    float* bdot   = ws + off; off += 16;
    bf16*  h_p    = (bf16*)(ws + off); off += ((size_t)Np*128 + 1)/2;
    bf16*  h_d    = (bf16*)(ws + off); off += ((size_t)Nd*128 + 1)/2;
    (void)n_in; (void)out_size; (void)ws_size; (void)off;

    hipMemsetAsync(d_ws, 0, zero_len*sizeof(float), stream);

    // fold attention into adm projection; thin GEMM for a_d (h_adm never built)
    prep_fold<<<1,128,0,stream>>>(Wa, ba, atd_pa, atd_da, Wf, bdot);
    {
        const int nt = (Na + 15)/16;
        afold_kernel<<<imin(nt,4096),256,0,stream>>>(x_adm, Wf, bdot,
                                                     a_d_pa, a_d_da, Na, nt);
    }
    // pat/diag projections (h stored bf16 + a_s dots)
    {
        const int nt = (Np + 31)/32;
        proj64<<<imin(nt,1024),256,0,stream>>>(x_pat, Wp, bp, ats_pa, h_p, a_s_pa, Np, nt);
    }
    {
        const int nt = (Nd + 31)/32;
        proj64<<<imin(nt,1024),256,0,stream>>>(x_diag, Wd, bd, ats_da, h_d, a_s_da, Nd, nt);
    }

    // edge aggregation (2 edges per 256-thread block)
    edge_kernel<<<(Epa+1)/2, 256, 0, stream>>>(e_pa_src, e_pa_dst, Epa,
                                               a_s_pa, a_d_pa, h_p, s_pa, o_pa);
    edge_kernel<<<(Eda+1)/2, 256, 0, stream>>>(e_da_src, e_da_dst, Eda,
                                               a_s_da, a_d_da, h_d, s_da, o_da);

    // semantic attention (MFMA; normalization fused into staging)
    {
        const int nt = (Na + 63)/64;
        dim3 grid(imin(nt,1024), 2);
        semw_mfma<<<grid, 256, 0, stream>>>(o_pa, o_da, s_pa, s_da, Wk, bk, wsum, Na, nt);
    }
    beta_kernel<<<1,128,0,stream>>>(wsum, q, beta, 1.f/(float)Na);

    // combine (normalization fused) + classifier + softmax
    final_kernel<<<(Na+3)/4, 256, 0, stream>>>(o_pa, o_da, s_pa, s_da, beta,
                                               Wl, bl, (float*)d_out, Na);
}